// Round 5
// baseline (518.518 us; speedup 1.0000x reference)
//
#include <hip/hip_runtime.h>
#include <cstdint>
#include <cstddef>

// SimpleGCN: h = x@W1+b1; 3x GCNConv(sym-norm adj w/ self loops); sigmoid(h@W2+b2)
// N=100000, d=128, E=1.6M.
// R5: (a) aggregate processes EDGE PAIRS: 32-lane halves, uint2 (4-feat) gathers
//     -> half the load instrs + deeper MLP; shfl_xor(32) combine in epilogue.
//     (b) scatter vectorized 4 edges/thread.
//     Histo kept: measured device atomic rate ~22G/s (R2 vs R4) => 74us is the
//     atomic-rate floor for 1 atomic/edge.

typedef __attribute__((ext_vector_type(8))) short bf16x8;
typedef __attribute__((ext_vector_type(4))) float f32x4;

// ---------- bf16 helpers (packed dword: low 16 bits = element 0) ----------
__device__ __forceinline__ unsigned f2bf(float f) {      // RNE float->bf16 bits
    unsigned u = __float_as_uint(f);
    u += 0x7fffu + ((u >> 16) & 1u);
    return u >> 16;
}
__device__ __forceinline__ float bf_lo(unsigned p) { return __uint_as_float(p << 16); }
__device__ __forceinline__ float bf_hi(unsigned p) { return __uint_as_float(p & 0xffff0000u); }

// ---------- histo + rank: ONE u64 atomic per edge, rank = returned old count ----------
// packed[c] = (in_count << 40) | sum(ew * 2^24)   (sum < 2^40 for deg < 64k)
__global__ void histo_kernel(const int* __restrict__ col, const float* __restrict__ ew,
                             unsigned long long* __restrict__ packed,
                             unsigned short* __restrict__ rank, int E) {
    int e = blockIdx.x * blockDim.x + threadIdx.x;
    if (e < E) {
        int c = col[e];
        unsigned long long v = (1ull << 40) |
            (unsigned long long)(unsigned)(ew[e] * 16777216.0f);
        unsigned long long old = atomicAdd(&packed[c], v);
        rank[e] = (unsigned short)(old >> 40);
    }
}

// ---------- 3-phase exclusive scan over PADDED counts (round up to x8) ----------
__global__ __launch_bounds__(256) void scan1_kernel(const unsigned long long* __restrict__ packed,
                                                    int* __restrict__ bsum, int n) {
    __shared__ int s[256];
    int b = blockIdx.x, t = threadIdx.x;
    int base = b * 1024 + t * 4;
    int acc = 0;
#pragma unroll
    for (int i = 0; i < 4; ++i)
        if (base + i < n) acc += ((int)(packed[base + i] >> 40) + 7) & ~7;
    s[t] = acc;
    __syncthreads();
    for (int off = 128; off > 0; off >>= 1) {
        if (t < off) s[t] += s[t + off];
        __syncthreads();
    }
    if (t == 0) bsum[b] = s[0];
}

__global__ __launch_bounds__(256) void scan2_kernel(int* __restrict__ bsum, int nblk) {
    __shared__ int s[256];
    int t = threadIdx.x;
    int v = (t < nblk) ? bsum[t] : 0;
    s[t] = v;
    __syncthreads();
    for (int off = 1; off < 256; off <<= 1) {
        int u = (t >= off) ? s[t - off] : 0;
        __syncthreads();
        s[t] += u;
        __syncthreads();
    }
    if (t < nblk) bsum[t] = s[t] - v;   // exclusive
}

// phase 3: row_ptr (padded) + dinv
__global__ __launch_bounds__(256) void scan3_kernel(const unsigned long long* __restrict__ packed,
                                                    const int* __restrict__ boff,
                                                    int* __restrict__ row_ptr,
                                                    float* __restrict__ dinv,
                                                    int n, int nblk) {
    __shared__ int s[256];
    int b = blockIdx.x, t = threadIdx.x;
    int base = b * 1024 + t * 4;
    int v[4];
#pragma unroll
    for (int i = 0; i < 4; ++i) {
        unsigned long long p = (base + i < n) ? packed[base + i] : 0ull;
        v[i] = (((int)(p >> 40)) + 7) & ~7;   // padded count
        if (base + i < n) {
            float deg = 1.0f + (float)(p & 0xFFFFFFFFFFull) * (1.0f / 16777216.0f);
            dinv[base + i] = rsqrtf(deg);
        }
    }
    s[t] = v[0] + v[1] + v[2] + v[3];
    __syncthreads();
    for (int off = 1; off < 256; off <<= 1) {
        int u = (t >= off) ? s[t - off] : 0;
        __syncthreads();
        s[t] += u;
        __syncthreads();
    }
    int run = boff[b] + ((t == 0) ? 0 : s[t - 1]);
#pragma unroll
    for (int i = 0; i < 4; ++i) {
        if (base + i < n) { row_ptr[base + i] = run; run += v[i]; }
    }
    if (b == nblk - 1 && t == 255) row_ptr[n] = boff[b] + s[255];
}

// ---------- scatter (NO atomics), 4 edges/thread ----------
// record = (src << 15) | (bf16(norm) & 0x7fff); norm > 0 so sign bit unused.
__global__ void scatter_kernel(const int* __restrict__ row, const int* __restrict__ col,
                               const float* __restrict__ ew, const float* __restrict__ dinv,
                               const int* __restrict__ row_ptr,
                               const unsigned short* __restrict__ rank,
                               unsigned* __restrict__ edata, int E) {
    int e0 = (blockIdx.x * blockDim.x + threadIdx.x) * 4;
    if (e0 + 3 < E) {
        int4   r4 = *(const int4*)(row + e0);
        int4   c4 = *(const int4*)(col + e0);
        float4 w4 = *(const float4*)(ew + e0);
        ushort4 k4 = *(const ushort4*)(rank + e0);
        int   r[4] = {r4.x, r4.y, r4.z, r4.w};
        int   c[4] = {c4.x, c4.y, c4.z, c4.w};
        float w[4] = {w4.x, w4.y, w4.z, w4.w};
        unsigned short kk[4] = {k4.x, k4.y, k4.z, k4.w};
#pragma unroll
        for (int i = 0; i < 4; ++i) {
            float nrm = dinv[r[i]] * w[i] * dinv[c[i]];
            int pos = row_ptr[c[i]] + (int)kk[i];
            edata[pos] = ((unsigned)r[i] << 15) | (f2bf(nrm) & 0x7fffu);
        }
    } else {
        for (int e = e0; e < E; ++e) {
            int r = row[e], c = col[e];
            float nrm = dinv[r] * ew[e] * dinv[c];
            int pos = row_ptr[c] + (int)rank[e];
            edata[pos] = ((unsigned)r << 15) | (f2bf(nrm) & 0x7fffu);
        }
    }
}

// ---------- weight prep: Wt[l][n][k] = bf16(W_l[k][n]), l=0:W1, 1..3:Wg ----------
__global__ void prep_weights_kernel(const float* __restrict__ W1, const float* __restrict__ Wg,
                                    unsigned short* __restrict__ Wt) {
    int idx = blockIdx.x * blockDim.x + threadIdx.x;   // 0..65535
    int l = idx >> 14, n = (idx >> 7) & 127, k = idx & 127;
    const float* W = (l == 0) ? W1 : (Wg + (size_t)(l - 1) * 16384);
    Wt[idx] = (unsigned short)f2bf(W[k * 128 + n]);
}

// ---------- MFMA GEMM: C[n x 128](bf16) = A[n x 128] @ W (+bias) ----------
// No LDS, no barriers: per wave 32x128 tile; B (Wt) is L1/L2-resident.
template<bool A_FP32>
__global__ __launch_bounds__(256) void gemm_mfma_kernel(const void* __restrict__ Av,
                                                        const unsigned short* __restrict__ Wt,
                                                        const float* __restrict__ bias,
                                                        unsigned short* __restrict__ C, int n) {
    int tid = threadIdx.x;
    int wave = tid >> 6, lane = tid & 63;
    int lm = lane & 15, g = lane >> 4;
    int m_base = blockIdx.x * 128 + wave * 32;

    f32x4 acc[2][8];
#pragma unroll
    for (int rt = 0; rt < 2; ++rt)
#pragma unroll
        for (int ct = 0; ct < 8; ++ct) acc[rt][ct] = (f32x4){0.f, 0.f, 0.f, 0.f};

    size_t rowA[2];
    rowA[0] = (size_t)min(m_base + lm, n - 1);
    rowA[1] = (size_t)min(m_base + 16 + lm, n - 1);

#pragma unroll
    for (int kc = 0; kc < 4; ++kc) {
        int k0 = kc * 32 + g * 8;
        bf16x8 a[2];
        if (A_FP32) {
            const float* A = (const float*)Av;
#pragma unroll
            for (int rt = 0; rt < 2; ++rt) {
                const float* p = A + rowA[rt] * 128 + k0;
                float f[8];
                *(float4*)&f[0] = *(const float4*)p;
                *(float4*)&f[4] = *(const float4*)(p + 4);
                short sv[8];
#pragma unroll
                for (int j = 0; j < 8; ++j) sv[j] = (short)f2bf(f[j]);
                a[rt] = *(bf16x8*)sv;
            }
        } else {
            const unsigned short* A = (const unsigned short*)Av;
#pragma unroll
            for (int rt = 0; rt < 2; ++rt)
                a[rt] = *(const bf16x8*)(A + rowA[rt] * 128 + k0);
        }
        bf16x8 b[8];
#pragma unroll
        for (int ct = 0; ct < 8; ++ct)
            b[ct] = *(const bf16x8*)(Wt + (ct * 16 + lm) * 128 + k0);
#pragma unroll
        for (int ct = 0; ct < 8; ++ct) {
            acc[0][ct] = __builtin_amdgcn_mfma_f32_16x16x32_bf16(a[0], b[ct], acc[0][ct], 0, 0, 0);
            acc[1][ct] = __builtin_amdgcn_mfma_f32_16x16x32_bf16(a[1], b[ct], acc[1][ct], 0, 0, 0);
        }
    }

#pragma unroll
    for (int rt = 0; rt < 2; ++rt) {
#pragma unroll
        for (int r = 0; r < 4; ++r) {
            int grow = m_base + rt * 16 + g * 4 + r;
            if (grow < n) {
#pragma unroll
                for (int ct = 0; ct < 8; ++ct) {
                    float v = acc[rt][ct][r];
                    if (bias) v += bias[ct * 16 + lm];
                    C[(size_t)grow * 128 + ct * 16 + lm] = (unsigned short)f2bf(v);
                }
            }
        }
    }
}

// ---------- aggregation: one wave per dest node, EDGE-PAIR batched gather ----------
// Wave = two 32-lane halves; half h processes edges j+h of each pair; lane's
// feature group fl = lane&31 covers feats 4*fl..4*fl+3 via one uint2 (dwordx2).
// Buckets padded to x8 (pad = src 0 / norm 0). Epilogue combines halves via
// shfl_xor(32); lanes 32-63 then mirror lanes 0-31.
template<bool FINAL>
__global__ __launch_bounds__(256) void aggregate_kernel(const uint2* __restrict__ tb2,
                                                        const int* __restrict__ row_ptr,
                                                        const unsigned* __restrict__ edata,
                                                        const float* __restrict__ dinv,
                                                        const float* __restrict__ bias,
                                                        const float* __restrict__ W2,
                                                        const float* __restrict__ b2,
                                                        void* __restrict__ out, int n) {
    int wid  = (int)((blockIdx.x * (size_t)blockDim.x + threadIdx.x) >> 6);
    int lane = threadIdx.x & 63;
    if (wid >= n) return;
    int half = lane >> 5;     // which edge of each pair
    int fl   = lane & 31;     // feature group (4 feats)

    float a0 = 0.f, a1 = 0.f, a2 = 0.f, a3 = 0.f;

    int start = row_ptr[wid], end = row_ptr[wid + 1];
    for (int base = start; base < end; base += 64) {
        unsigned ed = edata[base + lane];     // over-read into next buckets is harmless
        int m = end - base; if (m > 64) m = 64;
        int j = 0;
        for (; j + 16 <= m; j += 16) {        // 8 pairs = 16 edges
            unsigned p[8]; uint2 u[8];
#pragma unroll
            for (int k = 0; k < 8; ++k) p[k] = __shfl(ed, j + 2 * k + half);
#pragma unroll
            for (int k = 0; k < 8; ++k) u[k] = tb2[(size_t)(p[k] >> 15) * 32 + fl];
#pragma unroll
            for (int k = 0; k < 8; ++k) {
                float w = __uint_as_float((p[k] & 0x7fffu) << 16);
                a0 += w * bf_lo(u[k].x); a1 += w * bf_hi(u[k].x);
                a2 += w * bf_lo(u[k].y); a3 += w * bf_hi(u[k].y);
            }
        }
        for (; j < m; j += 8) {               // 4 pairs = 8 edges (m is mult of 8)
            unsigned p[4]; uint2 u[4];
#pragma unroll
            for (int k = 0; k < 4; ++k) p[k] = __shfl(ed, j + 2 * k + half);
#pragma unroll
            for (int k = 0; k < 4; ++k) u[k] = tb2[(size_t)(p[k] >> 15) * 32 + fl];
#pragma unroll
            for (int k = 0; k < 4; ++k) {
                float w = __uint_as_float((p[k] & 0x7fffu) << 16);
                a0 += w * bf_lo(u[k].x); a1 += w * bf_hi(u[k].x);
                a2 += w * bf_lo(u[k].y); a3 += w * bf_hi(u[k].y);
            }
        }
    }
    // combine the two halves (lanes l and l^32 end up with identical sums)
    a0 += __shfl_xor(a0, 32); a1 += __shfl_xor(a1, 32);
    a2 += __shfl_xor(a2, 32); a3 += __shfl_xor(a3, 32);

    // self-loop + bias (mirrored across halves; only low half stores)
    float di = dinv[wid];
    float sn = di * di;
    uint2 ts = tb2[(size_t)wid * 32 + fl];
    a0 += sn * bf_lo(ts.x); a1 += sn * bf_hi(ts.x);
    a2 += sn * bf_lo(ts.y); a3 += sn * bf_hi(ts.y);
    float4 bb = ((const float4*)bias)[fl];
    a0 += bb.x; a1 += bb.y; a2 += bb.z; a3 += bb.w;

    if (FINAL) {
        float4 wv = ((const float4*)W2)[fl];
        float d = a0 * wv.x + a1 * wv.y + a2 * wv.z + a3 * wv.w;
        if (half) d = 0.f;                    // halves mirror: count once
#pragma unroll
        for (int off = 32; off > 0; off >>= 1) d += __shfl_xor(d, off);
        if (lane == 0) ((float*)out)[wid] = 1.0f / (1.0f + expf(-(d + b2[0])));
    } else if (half == 0) {
        uint2 o;
        o.x = f2bf(a0) | (f2bf(a1) << 16);
        o.y = f2bf(a2) | (f2bf(a3) << 16);
        ((uint2*)out)[(size_t)wid * 32 + fl] = o;
    }
}

static inline char* align16(char* p) { return (char*)(((uintptr_t)p + 15) & ~(uintptr_t)15); }

extern "C" void kernel_launch(void* const* d_in, const int* in_sizes, int n_in,
                              void* d_out, int out_size, void* d_ws, size_t ws_size,
                              hipStream_t stream) {
    const float* x  = (const float*)d_in[0];
    const int*   ei = (const int*)d_in[1];   // [2, E] int32
    const float* ea = (const float*)d_in[2]; // [E]
    const float* W1 = (const float*)d_in[3];
    const float* b1 = (const float*)d_in[4];
    const float* Wg = (const float*)d_in[5]; // [3,128,128]
    const float* bg = (const float*)d_in[6]; // [3,128]
    const float* W2 = (const float*)d_in[7]; // [128]
    const float* b2 = (const float*)d_in[8]; // [1]

    const int N = in_sizes[0] / 128;
    const int E = in_sizes[2];
    const int Npad = (N + 127) & ~127;
    const int* row = ei;
    const int* col = ei + E;

    // workspace layout
    char* p = (char*)d_ws;
    unsigned short* hbuf = (unsigned short*)p; p += (size_t)Npad * 128 * 2;  // bf16 state
    unsigned short* tbuf = (unsigned short*)p; p += (size_t)Npad * 128 * 2;  // bf16 messages
    unsigned short* wbuf = (unsigned short*)p; p += 4 * 16384 * 2;           // bf16 W^T x4
    p = align16(p);
    unsigned long long* packed = (unsigned long long*)p; p += (size_t)N * 8;
    float* dinv   = (float*)p; p += (size_t)N * 4;
    int* row_ptr  = (int*)p;   p += (size_t)(N + 1) * 4; p = align16(p);
    int* bsum     = (int*)p;   p += 256 * 4;
    unsigned short* rank = (unsigned short*)p; p += (size_t)E * 2; p = align16(p);
    unsigned* edata = (unsigned*)p;                    // E + 7N + 64 padded records
    size_t edata_n = (size_t)E + 7 * (size_t)N + 64;

    dim3 b256(256);
    int nblk = (N + 1023) / 1024;   // 98 (scan2 handles <=256)

    hipMemsetAsync(packed, 0, (size_t)N * 8, stream);
    hipMemsetAsync(edata, 0, edata_n * 4, stream);
    prep_weights_kernel<<<256, b256, 0, stream>>>(W1, Wg, wbuf);
    histo_kernel  <<<(E + 255) / 256, b256, 0, stream>>>(col, ea, packed, rank, E);
    scan1_kernel  <<<nblk, b256, 0, stream>>>(packed, bsum, N);
    scan2_kernel  <<<1, b256, 0, stream>>>(bsum, nblk);
    scan3_kernel  <<<nblk, b256, 0, stream>>>(packed, bsum, row_ptr, dinv, N, nblk);
    scatter_kernel<<<(E / 4 + 255) / 256 + 1, b256, 0, stream>>>(row, col, ea, dinv, row_ptr, rank, edata, E);

    int gemm_blocks = Npad / 128;
    int wave_blocks = (int)(((size_t)N * 64 + 255) / 256);

    gemm_mfma_kernel<true><<<gemm_blocks, b256, 0, stream>>>(x, wbuf, b1, hbuf, N);
    for (int l = 0; l < 3; ++l) {
        gemm_mfma_kernel<false><<<gemm_blocks, b256, 0, stream>>>(hbuf, wbuf + (size_t)(l + 1) * 16384,
                                                                  nullptr, tbuf, N);
        if (l < 2) {
            aggregate_kernel<false><<<wave_blocks, b256, 0, stream>>>(
                (const uint2*)tbuf, row_ptr, edata, dinv, bg + (size_t)l * 128,
                nullptr, nullptr, hbuf, N);
        } else {
            aggregate_kernel<true><<<wave_blocks, b256, 0, stream>>>(
                (const uint2*)tbuf, row_ptr, edata, dinv, bg + (size_t)l * 128,
                W2, b2, d_out, N);
        }
    }
}

// Round 7
// 507.932 us; speedup vs baseline: 1.0208x; 1.0208x over previous
//
#include <hip/hip_runtime.h>
#include <cstdint>
#include <cstddef>

// SimpleGCN: h = x@W1+b1; 3x GCNConv(sym-norm adj w/ self loops); sigmoid(h@W2+b2)
// N=100000, d=128, E=1.6M.
// R7 = R6 (DAG-fused launches) + REPLAY-STABLE NUMERICS:
//   R6 failed post-timing re-validation: histo-atomic bucket order is
//   non-deterministic across graph replays; with bf16 h-state a 1-ulp fp32 sum
//   difference re-quantizes h (+-0.4%) and cascades (absmax 0.0039 -> 0.0117).
//   Fix: h state fp32 end-to-end (aggregate writes fp32; GEMMs convert A
//   fp32->bf16 in-register). Messages (the gather traffic floor) stay bf16.
// Kept from R6: fusedA = histo || gemm1, fusedE = scatter || gemm2, 2-phase scan.

typedef __attribute__((ext_vector_type(8))) short bf16x8;
typedef __attribute__((ext_vector_type(4))) float f32x4;

// ---------- bf16 helpers (packed dword: low 16 bits = element 0) ----------
__device__ __forceinline__ unsigned f2bf(float f) {      // RNE float->bf16 bits
    unsigned u = __float_as_uint(f);
    u += 0x7fffu + ((u >> 16) & 1u);
    return u >> 16;
}
__device__ __forceinline__ float bf_lo(unsigned p) { return __uint_as_float(p << 16); }
__device__ __forceinline__ float bf_hi(unsigned p) { return __uint_as_float(p & 0xffff0000u); }

// ---------- weight prep: Wt[l][n][k] = bf16(W_l[k][n]), l=0:W1, 1..3:Wg ----------
__global__ void prep_weights_kernel(const float* __restrict__ W1, const float* __restrict__ Wg,
                                    unsigned short* __restrict__ Wt) {
    int idx = blockIdx.x * blockDim.x + threadIdx.x;   // 0..65535
    int l = idx >> 14, n = (idx >> 7) & 127, k = idx & 127;
    const float* W = (l == 0) ? W1 : (Wg + (size_t)(l - 1) * 16384);
    Wt[idx] = (unsigned short)f2bf(W[k * 128 + n]);
}

// ---------- GEMM body: C[n x 128] = A[n x 128](fp32) @ W (+bias) ----------
// No LDS, no barriers: per wave 32x128 tile; B (Wt) is L1/L2-resident.
// A is fp32, converted to bf16 in-register. C is bf16 (messages) or fp32 (h).
template<bool C_BF16>
__device__ __forceinline__ void gemm_body(const float* __restrict__ A,
                                          const unsigned short* __restrict__ Wt,
                                          const float* __restrict__ bias,
                                          void* __restrict__ C, int n, int blk) {
    int tid = threadIdx.x;
    int wave = tid >> 6, lane = tid & 63;
    int lm = lane & 15, g = lane >> 4;
    int m_base = blk * 128 + wave * 32;

    f32x4 acc[2][8];
#pragma unroll
    for (int rt = 0; rt < 2; ++rt)
#pragma unroll
        for (int ct = 0; ct < 8; ++ct) acc[rt][ct] = (f32x4){0.f, 0.f, 0.f, 0.f};

    size_t rowA[2];
    rowA[0] = (size_t)min(m_base + lm, n - 1);
    rowA[1] = (size_t)min(m_base + 16 + lm, n - 1);

#pragma unroll
    for (int kc = 0; kc < 4; ++kc) {
        int k0 = kc * 32 + g * 8;
        bf16x8 a[2];
#pragma unroll
        for (int rt = 0; rt < 2; ++rt) {
            const float* p = A + rowA[rt] * 128 + k0;
            float f[8];
            *(float4*)&f[0] = *(const float4*)p;
            *(float4*)&f[4] = *(const float4*)(p + 4);
            short sv[8];
#pragma unroll
            for (int j = 0; j < 8; ++j) sv[j] = (short)f2bf(f[j]);
            a[rt] = *(bf16x8*)sv;
        }
        bf16x8 b[8];
#pragma unroll
        for (int ct = 0; ct < 8; ++ct)
            b[ct] = *(const bf16x8*)(Wt + (ct * 16 + lm) * 128 + k0);
#pragma unroll
        for (int ct = 0; ct < 8; ++ct) {
            acc[0][ct] = __builtin_amdgcn_mfma_f32_16x16x32_bf16(a[0], b[ct], acc[0][ct], 0, 0, 0);
            acc[1][ct] = __builtin_amdgcn_mfma_f32_16x16x32_bf16(a[1], b[ct], acc[1][ct], 0, 0, 0);
        }
    }

#pragma unroll
    for (int rt = 0; rt < 2; ++rt) {
#pragma unroll
        for (int r = 0; r < 4; ++r) {
            int grow = m_base + rt * 16 + g * 4 + r;
            if (grow < n) {
#pragma unroll
                for (int ct = 0; ct < 8; ++ct) {
                    float v = acc[rt][ct][r];
                    if (bias) v += bias[ct * 16 + lm];
                    if (C_BF16)
                        ((unsigned short*)C)[(size_t)grow * 128 + ct * 16 + lm] = (unsigned short)f2bf(v);
                    else
                        ((float*)C)[(size_t)grow * 128 + ct * 16 + lm] = v;
                }
            }
        }
    }
}

// ---------- scatter body (NO atomics): pos = row_ptr[c] + rank[e], 4 edges/thread ----------
// record = (src << 15) | (bf16(norm) & 0x7fff); norm > 0 so sign bit unused.
__device__ __forceinline__ void scatter_body(const int* __restrict__ row, const int* __restrict__ col,
                                             const float* __restrict__ ew, const float* __restrict__ dinv,
                                             const int* __restrict__ row_ptr,
                                             const unsigned short* __restrict__ rank,
                                             unsigned* __restrict__ edata, int E, int blk) {
    int e0 = (blk * 256 + threadIdx.x) * 4;
    if (e0 + 3 < E) {
        int4   r4 = *(const int4*)(row + e0);
        int4   c4 = *(const int4*)(col + e0);
        float4 w4 = *(const float4*)(ew + e0);
        ushort4 k4 = *(const ushort4*)(rank + e0);
        int   r[4] = {r4.x, r4.y, r4.z, r4.w};
        int   c[4] = {c4.x, c4.y, c4.z, c4.w};
        float w[4] = {w4.x, w4.y, w4.z, w4.w};
        unsigned short kk[4] = {k4.x, k4.y, k4.z, k4.w};
#pragma unroll
        for (int i = 0; i < 4; ++i) {
            float nrm = dinv[r[i]] * w[i] * dinv[c[i]];
            int pos = row_ptr[c[i]] + (int)kk[i];
            edata[pos] = ((unsigned)r[i] << 15) | (f2bf(nrm) & 0x7fffu);
        }
    } else {
        for (int e = e0; e < E; ++e) {
            int r = row[e], c = col[e];
            float nrm = dinv[r] * ew[e] * dinv[c];
            int pos = row_ptr[c] + (int)rank[e];
            edata[pos] = ((unsigned)r << 15) | (f2bf(nrm) & 0x7fffu);
        }
    }
}

// ---------- fused A: histo (1 u64 atomic/edge + rank) || gemm1 (x@W1+b1 -> fp32 h) ----------
// gemm blocks are b % K == 0 (b/K < nGemm); the rest are histo blocks.
__global__ __launch_bounds__(256) void fusedA_kernel(const int* __restrict__ col,
                                                     const float* __restrict__ ewa,
                                                     unsigned long long* __restrict__ packed,
                                                     unsigned short* __restrict__ rank, int E,
                                                     const float* __restrict__ x,
                                                     const unsigned short* __restrict__ Wt0,
                                                     const float* __restrict__ b1,
                                                     float* __restrict__ hbuf, int n,
                                                     int nGemm, int K) {
    int b = blockIdx.x;
    int g = b / K, r = b - g * K;
    if (r == 0 && g < nGemm) {
        gemm_body<false>(x, Wt0, b1, hbuf, n, g);
    } else {
        int hb = b - min(g + (r > 0 ? 1 : 0), nGemm);
        int e = hb * 256 + threadIdx.x;
        if (e < E) {
            int c = col[e];
            unsigned long long v = (1ull << 40) |
                (unsigned long long)(unsigned)(ewa[e] * 16777216.0f);
            unsigned long long old = atomicAdd(&packed[c], v);
            rank[e] = (unsigned short)(old >> 40);
        }
    }
}

// ---------- fused E: scatter || gemm2 (hbuf@Wg0 -> tbuf bf16) ----------
__global__ __launch_bounds__(256) void fusedE_kernel(const int* __restrict__ row,
                                                     const int* __restrict__ col,
                                                     const float* __restrict__ ewa,
                                                     const float* __restrict__ dinv,
                                                     const int* __restrict__ row_ptr,
                                                     const unsigned short* __restrict__ rank,
                                                     unsigned* __restrict__ edata, int E,
                                                     const float* __restrict__ hbuf,
                                                     const unsigned short* __restrict__ Wt1,
                                                     unsigned short* __restrict__ tbuf, int n,
                                                     int nGemm, int K) {
    int b = blockIdx.x;
    int g = b / K, r = b - g * K;
    if (r == 0 && g < nGemm) {
        gemm_body<true>(hbuf, Wt1, nullptr, tbuf, n, g);
    } else {
        int sb = b - min(g + (r > 0 ? 1 : 0), nGemm);
        scatter_body(row, col, ewa, dinv, row_ptr, rank, edata, E, sb);
    }
}

// ---------- standalone GEMM (layers 2,3 messages): fp32 A -> bf16 C ----------
__global__ __launch_bounds__(256) void gemm_mfma_kernel(const float* __restrict__ A,
                                                        const unsigned short* __restrict__ Wt,
                                                        unsigned short* __restrict__ C, int n) {
    gemm_body<true>(A, Wt, nullptr, C, n, blockIdx.x);
}

// ---------- scan phase 1: per-1024-chunk sums of PADDED counts (x8) ----------
__global__ __launch_bounds__(256) void scan1_kernel(const unsigned long long* __restrict__ packed,
                                                    int* __restrict__ bsum, int n) {
    __shared__ int s[256];
    int b = blockIdx.x, t = threadIdx.x;
    int base = b * 1024 + t * 4;
    int acc = 0;
#pragma unroll
    for (int i = 0; i < 4; ++i)
        if (base + i < n) acc += ((int)(packed[base + i] >> 40) + 7) & ~7;
    s[t] = acc;
    __syncthreads();
    for (int off = 128; off > 0; off >>= 1) {
        if (t < off) s[t] += s[t + off];
        __syncthreads();
    }
    if (t == 0) bsum[b] = s[0];
}

// ---------- scan phase 3 (phase 2 folded in): row_ptr (padded) + dinv ----------
__global__ __launch_bounds__(256) void scan3_kernel(const unsigned long long* __restrict__ packed,
                                                    const int* __restrict__ bsum,
                                                    int* __restrict__ row_ptr,
                                                    float* __restrict__ dinv,
                                                    int n, int nblk) {
    __shared__ int s[256];
    int b = blockIdx.x, t = threadIdx.x;

    // phase A: every block redundantly computes inclusive prefix of bsum (nblk<=256)
    int bv = (t < nblk) ? bsum[t] : 0;
    s[t] = bv;
    __syncthreads();
    for (int off = 1; off < 256; off <<= 1) {
        int u = (t >= off) ? s[t - off] : 0;
        __syncthreads();
        s[t] += u;
        __syncthreads();
    }
    int boffb = (b == 0) ? 0 : s[b - 1];
    int total = s[nblk - 1];
    __syncthreads();

    // phase B: local scan of this block's 1024 padded counts
    int base = b * 1024 + t * 4;
    int v[4];
#pragma unroll
    for (int i = 0; i < 4; ++i) {
        unsigned long long p = (base + i < n) ? packed[base + i] : 0ull;
        v[i] = (((int)(p >> 40)) + 7) & ~7;   // padded count
        if (base + i < n) {
            float deg = 1.0f + (float)(p & 0xFFFFFFFFFFull) * (1.0f / 16777216.0f);
            dinv[base + i] = rsqrtf(deg);
        }
    }
    s[t] = v[0] + v[1] + v[2] + v[3];
    __syncthreads();
    for (int off = 1; off < 256; off <<= 1) {
        int u = (t >= off) ? s[t - off] : 0;
        __syncthreads();
        s[t] += u;
        __syncthreads();
    }
    int run = boffb + ((t == 0) ? 0 : s[t - 1]);
#pragma unroll
    for (int i = 0; i < 4; ++i) {
        if (base + i < n) { row_ptr[base + i] = run; run += v[i]; }
    }
    if (b == nblk - 1 && t == 255) row_ptr[n] = total;
}

// ---------- aggregation: one wave per dest node, edge-pair batched gather ----------
// Gathers bf16 messages (tb2); accumulates fp32; writes fp32 h (or final sigmoid).
template<bool FINAL>
__global__ __launch_bounds__(256) void aggregate_kernel(const uint2* __restrict__ tb2,
                                                        const int* __restrict__ row_ptr,
                                                        const unsigned* __restrict__ edata,
                                                        const float* __restrict__ dinv,
                                                        const float* __restrict__ bias,
                                                        const float* __restrict__ W2,
                                                        const float* __restrict__ b2,
                                                        void* __restrict__ out, int n) {
    int wid  = (int)((blockIdx.x * (size_t)blockDim.x + threadIdx.x) >> 6);
    int lane = threadIdx.x & 63;
    if (wid >= n) return;
    int half = lane >> 5;     // which edge of each pair
    int fl   = lane & 31;     // feature group (4 feats)

    float a0 = 0.f, a1 = 0.f, a2 = 0.f, a3 = 0.f;

    int start = row_ptr[wid], end = row_ptr[wid + 1];
    for (int base = start; base < end; base += 64) {
        unsigned ed = edata[base + lane];     // over-read into next buckets is harmless
        int m = end - base; if (m > 64) m = 64;
        int j = 0;
        for (; j + 16 <= m; j += 16) {        // 8 pairs = 16 edges
            unsigned p[8]; uint2 u[8];
#pragma unroll
            for (int k = 0; k < 8; ++k) p[k] = __shfl(ed, j + 2 * k + half);
#pragma unroll
            for (int k = 0; k < 8; ++k) u[k] = tb2[(size_t)(p[k] >> 15) * 32 + fl];
#pragma unroll
            for (int k = 0; k < 8; ++k) {
                float w = __uint_as_float((p[k] & 0x7fffu) << 16);
                a0 += w * bf_lo(u[k].x); a1 += w * bf_hi(u[k].x);
                a2 += w * bf_lo(u[k].y); a3 += w * bf_hi(u[k].y);
            }
        }
        for (; j < m; j += 8) {               // 4 pairs = 8 edges (m is mult of 8)
            unsigned p[4]; uint2 u[4];
#pragma unroll
            for (int k = 0; k < 4; ++k) p[k] = __shfl(ed, j + 2 * k + half);
#pragma unroll
            for (int k = 0; k < 4; ++k) u[k] = tb2[(size_t)(p[k] >> 15) * 32 + fl];
#pragma unroll
            for (int k = 0; k < 4; ++k) {
                float w = __uint_as_float((p[k] & 0x7fffu) << 16);
                a0 += w * bf_lo(u[k].x); a1 += w * bf_hi(u[k].x);
                a2 += w * bf_lo(u[k].y); a3 += w * bf_hi(u[k].y);
            }
        }
    }
    // combine the two halves (lanes l and l^32 end up with identical sums)
    a0 += __shfl_xor(a0, 32); a1 += __shfl_xor(a1, 32);
    a2 += __shfl_xor(a2, 32); a3 += __shfl_xor(a3, 32);

    // self-loop + bias (mirrored across halves)
    float di = dinv[wid];
    float sn = di * di;
    uint2 ts = tb2[(size_t)wid * 32 + fl];
    a0 += sn * bf_lo(ts.x); a1 += sn * bf_hi(ts.x);
    a2 += sn * bf_lo(ts.y); a3 += sn * bf_hi(ts.y);
    float4 bb = ((const float4*)bias)[fl];
    a0 += bb.x; a1 += bb.y; a2 += bb.z; a3 += bb.w;

    if (FINAL) {
        float4 wv = ((const float4*)W2)[fl];
        float d = a0 * wv.x + a1 * wv.y + a2 * wv.z + a3 * wv.w;
        if (half) d = 0.f;                    // halves mirror: count once
#pragma unroll
        for (int off = 32; off > 0; off >>= 1) d += __shfl_xor(d, off);
        if (lane == 0) ((float*)out)[wid] = 1.0f / (1.0f + expf(-(d + b2[0])));
    } else if (half == 0) {
        float4 o; o.x = a0; o.y = a1; o.z = a2; o.w = a3;
        ((float4*)out)[(size_t)wid * 32 + fl] = o;   // fp32 h state
    }
}

static inline char* align16(char* p) { return (char*)(((uintptr_t)p + 15) & ~(uintptr_t)15); }

extern "C" void kernel_launch(void* const* d_in, const int* in_sizes, int n_in,
                              void* d_out, int out_size, void* d_ws, size_t ws_size,
                              hipStream_t stream) {
    const float* x  = (const float*)d_in[0];
    const int*   ei = (const int*)d_in[1];   // [2, E] int32
    const float* ea = (const float*)d_in[2]; // [E]
    const float* W1 = (const float*)d_in[3];
    const float* b1 = (const float*)d_in[4];
    const float* Wg = (const float*)d_in[5]; // [3,128,128]
    const float* bg = (const float*)d_in[6]; // [3,128]
    const float* W2 = (const float*)d_in[7]; // [128]
    const float* b2 = (const float*)d_in[8]; // [1]

    const int N = in_sizes[0] / 128;
    const int E = in_sizes[2];
    const int Npad = (N + 127) & ~127;
    const int* row = ei;
    const int* col = ei + E;

    // workspace layout
    char* p = (char*)d_ws;
    float*          hbuf = (float*)p;          p += (size_t)Npad * 128 * 4;  // fp32 state
    unsigned short* tbuf = (unsigned short*)p; p += (size_t)Npad * 128 * 2;  // bf16 messages
    unsigned short* wbuf = (unsigned short*)p; p += 4 * 16384 * 2;           // bf16 W^T x4
    p = align16(p);
    unsigned long long* packed = (unsigned long long*)p; p += (size_t)N * 8;
    float* dinv   = (float*)p; p += (size_t)N * 4;
    int* row_ptr  = (int*)p;   p += (size_t)(N + 1) * 4; p = align16(p);
    int* bsum     = (int*)p;   p += 256 * 4;
    unsigned short* rank = (unsigned short*)p; p += (size_t)E * 2; p = align16(p);
    unsigned* edata = (unsigned*)p;                    // E + 7N + 64 padded records
    size_t edata_n = (size_t)E + 7 * (size_t)N + 64;

    dim3 b256(256);
    int nblk  = (N + 1023) / 1024;          // 98 (<=256)
    int nGemm = Npad / 128;                 // 782
    int nHist = (E + 255) / 256;            // 6250
    int nScat = (E + 1023) / 1024;          // 1563

    int gridA = nHist + nGemm;
    int KA    = (gridA + nGemm - 1) / nGemm;   // 9
    int gridE = nScat + nGemm;
    int KE    = (gridE + nGemm - 1) / nGemm;   // 3

    hipMemsetAsync(packed, 0, (size_t)N * 8, stream);
    hipMemsetAsync(edata, 0, edata_n * 4, stream);
    prep_weights_kernel<<<256, b256, 0, stream>>>(W1, Wg, wbuf);

    fusedA_kernel<<<gridA, b256, 0, stream>>>(col, ea, packed, rank, E,
                                              x, wbuf, b1, hbuf, N, nGemm, KA);
    scan1_kernel <<<nblk, b256, 0, stream>>>(packed, bsum, N);
    scan3_kernel <<<nblk, b256, 0, stream>>>(packed, bsum, row_ptr, dinv, N, nblk);
    fusedE_kernel<<<gridE, b256, 0, stream>>>(row, col, ea, dinv, row_ptr, rank, edata, E,
                                              hbuf, wbuf + 16384, tbuf, N, nGemm, KE);

    int wave_blocks = (int)(((size_t)N * 64 + 255) / 256);

    // agg0 -> hbuf(fp32); gemm(l=1) -> tbuf; agg1 -> hbuf; gemm(l=2) -> tbuf; agg2 -> out
    aggregate_kernel<false><<<wave_blocks, b256, 0, stream>>>(
        (const uint2*)tbuf, row_ptr, edata, dinv, bg, nullptr, nullptr, hbuf, N);
    gemm_mfma_kernel<<<nGemm, b256, 0, stream>>>(hbuf, wbuf + 2 * 16384, tbuf, N);
    aggregate_kernel<false><<<wave_blocks, b256, 0, stream>>>(
        (const uint2*)tbuf, row_ptr, edata, dinv, bg + 128, nullptr, nullptr, hbuf, N);
    gemm_mfma_kernel<<<nGemm, b256, 0, stream>>>(hbuf, wbuf + 3 * 16384, tbuf, N);
    aggregate_kernel<true><<<wave_blocks, b256, 0, stream>>>(
        (const uint2*)tbuf, row_ptr, edata, dinv, bg + 256, W2, b2, d_out, N);
}